// Round 4
// baseline (211.777 us; speedup 1.0000x reference)
//
#include <hip/hip_runtime.h>
#include <stdint.h>

// CoefficientMaxPool: x [B=32, N=512, IR=16, C=128] f32.
// ll2[b,n,l,c] = sum_{i in degree l} x[b,n,i,c]^2 ; win[b,l,c] = argmax_n ll2
// out[b,i,c] = x[b, win[b,l(i),c], i, c]
//
// R4: SINGLE fused kernel, no workspace, no atomics.
//   grid = (b, cgroup) = 32 x 8 = 256 blocks (one per CU);
//   block = 256 threads = (nrow in [0,64)) x (c4 in [0,4)), covering a
//   16-channel slice. Each thread scans 8 neighbors (n = nrow + 64k),
//   16 independent float4 loads each; packed (val_bits<<32 | ~n) u64 argmax
//   (ll2 >= 0 -> float bits order-isomorphic; ~n ties -> smallest n, matching
//   jnp.argmax; ascending-i sum order -> bit-identical, absmax 0.0 in R1-R3).
//   Reduce: in-wave shfl_xor butterfly over 16 nrows, LDS across 4 waves,
//   decode winner n per (l,ch), gather + write 256 outputs.

constexpr int B_  = 32;
constexpr int N_  = 512;
constexpr int IR_ = 16;
constexpr int C_  = 128;
constexpr int NL_ = 4;

constexpr int CG_ = 8;               // channel groups
constexpr int CW_ = C_ / CG_;        // 16 channels per group (4 float4 lanes)
constexpr int NROW = 64;             // neighbor rows per block
constexpr int KN   = N_ / NROW;      // 8 n per thread

// irrep index -> degree l (LMAX=3, fixed by the reference setup)
__device__ constexpr int L_OF_I[16] = {0, 1,1,1, 2,2,2,2,2, 3,3,3,3,3,3,3};

__global__ __launch_bounds__(256)
void cmp_fused(const float* __restrict__ x, float* __restrict__ out) {
    const int t    = threadIdx.x;
    const int c4   = t & 3;          // float4 slot within the 16-ch group
    const int nrow = t >> 2;         // [0,64)
    const int wv   = t >> 6;         // wave id [0,4)
    const int b    = blockIdx.x;
    const int cg   = blockIdx.y;

    // float4-unit column offset of this thread within an irrep row
    const unsigned colf4 = (unsigned)(cg * 4 + c4);
    const float4* __restrict__ x4 = (const float4*)x;

    unsigned long long best[NL_][4];
#pragma unroll
    for (int l = 0; l < NL_; ++l)
#pragma unroll
        for (int j = 0; j < 4; ++j) best[l][j] = 0ull;   // below any candidate

    for (int k = 0; k < KN; ++k) {
        const int n = nrow + k * NROW;
        const unsigned base = ((unsigned)(b * N_ + n) * IR_) * 32u + colf4;

        float4 acc[NL_];
#pragma unroll
        for (int l = 0; l < NL_; ++l) { acc[l].x = acc[l].y = acc[l].z = acc[l].w = 0.f; }

#pragma unroll
        for (int i = 0; i < IR_; ++i) {
            const float4 v = x4[base + i * 32];
            const int l = L_OF_I[i];          // compile-time under full unroll
            acc[l].x += v.x * v.x;
            acc[l].y += v.y * v.y;
            acc[l].z += v.z * v.z;
            acc[l].w += v.w * v.w;
        }

        const unsigned long long code = (unsigned long long)(~(unsigned int)n);
#pragma unroll
        for (int l = 0; l < NL_; ++l) {
            const float vals[4] = {acc[l].x, acc[l].y, acc[l].z, acc[l].w};
#pragma unroll
            for (int j = 0; j < 4; ++j) {
                const unsigned long long p =
                    ((unsigned long long)__float_as_uint(vals[j]) << 32) | code;
                if (p > best[l][j]) best[l][j] = p;
            }
        }
    }

    // In-wave butterfly over the 16 nrows sharing this c4 (lane = nrow16*4+c4).
#pragma unroll
    for (int l = 0; l < NL_; ++l)
#pragma unroll
        for (int j = 0; j < 4; ++j) {
#pragma unroll
            for (int m = 4; m < 64; m <<= 1) {
                const unsigned long long q = __shfl_xor(best[l][j], m, 64);
                if (q > best[l][j]) best[l][j] = q;
            }
        }

    // Cross-wave reduce via LDS: 4 waves x (NL * CW) entries.
    __shared__ unsigned long long red[4][NL_ * CW_];     // 2 KiB
    __shared__ int nwin[NL_ * CW_];
    if ((t & 63) < 4) {                                  // lanes c4=0..3, nrow16==0
#pragma unroll
        for (int l = 0; l < NL_; ++l)
#pragma unroll
            for (int j = 0; j < 4; ++j)
                red[wv][l * CW_ + c4 * 4 + j] = best[l][j];
    }
    __syncthreads();

    if (t < NL_ * CW_) {                                 // 64 threads
        unsigned long long m = red[0][t];
#pragma unroll
        for (int w = 1; w < 4; ++w) {
            const unsigned long long v = red[w][t];
            if (v > m) m = v;
        }
        nwin[t] = (int)(~(unsigned int)(m & 0xFFFFFFFFull));
    }
    __syncthreads();

    // Gather + write: 256 outputs for this (b, cgroup): t = i*16 + ch.
    const int i  = t >> 4;
    const int ch = t & 15;
    const int n  = nwin[L_OF_I[i] * CW_ + ch];
    const int c  = cg * CW_ + ch;
    out[((b * IR_) + i) * C_ + c] = x[(((unsigned)(b * N_ + n) * IR_) + i) * C_ + c];
}

extern "C" void kernel_launch(void* const* d_in, const int* in_sizes, int n_in,
                              void* d_out, int out_size, void* d_ws, size_t ws_size,
                              hipStream_t stream) {
    const float* x = (const float*)d_in[0];
    // d_in[1] (i2l) is a fixed 0/1 indicator for LMAX=3 — hardcoded as L_OF_I.
    float* out = (float*)d_out;
    (void)d_ws; (void)ws_size;

    dim3 g(B_, CG_);
    cmp_fused<<<g, 256, 0, stream>>>(x, out);
}

// Round 5
// 187.851 us; speedup vs baseline: 1.1274x; 1.1274x over previous
//
#include <hip/hip_runtime.h>
#include <stdint.h>

// CoefficientMaxPool: x [B=32, N=512, IR=16, C=128] f32.
// ll2[b,n,l,c] = sum_{i in degree l} x[b,n,i,c]^2 ; win[b,l,c] = argmax_n ll2
// out[b,i,c] = x[b, win[b,l(i),c], i, c]
//
// Two-phase argmax over n, no atomics (best measured config, R2: 189.7 us).
//   phase1: each (chunk,b) block reduces its 16 n's to a packed
//           (value_bits<<32 | ~n) u64 per (l,c), plain-stores to ws[chunk][b][e].
//   phase2: reduce 32 chunks per (b,l,c), decode n, gather + write out.
// ll2 >= 0 so float bits are order-isomorphic; ~n breaks ties toward the
// SMALLEST n (first occurrence), matching jnp.argmax. Sum order over i is
// ascending, same as the einsum -> bit-identical f32 values (absmax 0.0,
// rounds 1-4).
//
// Session evidence (R1-R4): dur_us = ~155 us fixed harness term (512 MiB ws
// re-poison @77us + d_in restore + d_out poison, visible as fillBufferAligned
// in every profile) + ~35-45 us for these kernels, of which the mandatory
// 134 MB x-read @6.3 TB/s = 21 us floor. Atomics removal (R2), 4x occupancy
// (R3), and single-kernel fusion (R4, -16us occupancy/coalescing regression)
// all confirm phase1 is HBM-bound at ~25-35 us.

constexpr int B_  = 32;
constexpr int N_  = 512;
constexpr int IR_ = 16;
constexpr int C_  = 128;
constexpr int NL_ = 4;
constexpr int E_  = NL_ * C_;        // 512 entries per b

constexpr int NCHUNK = 32;           // n-chunks (grid.x)
constexpr int CHN    = N_ / NCHUNK;  // 16 n per chunk
constexpr int NROW   = 4;            // n-rows per block (thread t>>5)
constexpr int NN     = CHN / NROW;   // 4 n per thread

// irrep index -> degree l (LMAX=3, fixed by the reference setup)
__device__ constexpr int L_OF_I[16] = {0, 1,1,1, 2,2,2,2,2, 3,3,3,3,3,3,3};
__device__ constexpr int I0_OF_L[4] = {0, 1, 4, 9};   // first irrep of degree l
__device__ constexpr int NI_OF_L[4] = {1, 3, 5, 7};   // 2l+1

__global__ __launch_bounds__(128)
void cmp_phase1(const float* __restrict__ x, unsigned long long* __restrict__ ws) {
    const int t    = threadIdx.x;
    const int c4   = t & 31;     // float4 column group: c in [4*c4, 4*c4+4)
    const int nrow = t >> 5;     // which n-subrow
    const int chunk = blockIdx.x;
    const int b     = blockIdx.y;

    unsigned long long best[NL_][4];
#pragma unroll
    for (int l = 0; l < NL_; ++l)
#pragma unroll
        for (int j = 0; j < 4; ++j) best[l][j] = 0ull;  // below any real candidate

    const int n0 = chunk * CHN + nrow * NN;
    const float4* __restrict__ x4 = (const float4*)x;

#pragma unroll
    for (int nn = 0; nn < NN; ++nn) {
        const int n = n0 + nn;
        // float4-unit base index: ((b*N + n)*IR + i)*32 + c4
        const long base = ((long)(b * N_ + n) * IR_) * 32 + c4;

        float4 acc[NL_];
#pragma unroll
        for (int l = 0; l < NL_; ++l) { acc[l].x = acc[l].y = acc[l].z = acc[l].w = 0.f; }

#pragma unroll
        for (int i = 0; i < IR_; ++i) {
            const float4 v = x4[base + i * 32];
            const int l = L_OF_I[i];            // compile-time under full unroll
            acc[l].x += v.x * v.x;
            acc[l].y += v.y * v.y;
            acc[l].z += v.z * v.z;
            acc[l].w += v.w * v.w;
        }

        const unsigned long long code = (unsigned long long)(~(unsigned int)n);
#pragma unroll
        for (int l = 0; l < NL_; ++l) {
            const float vals[4] = {acc[l].x, acc[l].y, acc[l].z, acc[l].w};
#pragma unroll
            for (int j = 0; j < 4; ++j) {
                const unsigned long long p =
                    ((unsigned long long)__float_as_uint(vals[j]) << 32) | code;
                if (p > best[l][j]) best[l][j] = p;
            }
        }
    }

    // Reduce the 4 n-rows inside the block via LDS, then plain store per entry.
    __shared__ unsigned long long red[NROW][E_];   // 16 KiB
#pragma unroll
    for (int l = 0; l < NL_; ++l)
#pragma unroll
        for (int j = 0; j < 4; ++j)
            red[nrow][l * C_ + c4 * 4 + j] = best[l][j];
    __syncthreads();

    unsigned long long* __restrict__ wsp = ws + ((long)chunk * B_ + b) * E_;
#pragma unroll
    for (int k = 0; k < 4; ++k) {
        const int e = t + k * 128;               // entry in [0, E_)
        unsigned long long m = red[0][e];
#pragma unroll
        for (int nr = 1; nr < NROW; ++nr) {
            const unsigned long long v = red[nr][e];
            if (v > m) m = v;
        }
        wsp[e] = m;                               // coalesced, contention-free
    }
}

// grid: (B_, NL_) x 128 threads. Thread = (b, l, c). Reduce 32 chunks,
// decode winner n, gather the 2l+1 irrep rows of degree l.
__global__ __launch_bounds__(128)
void cmp_phase2(const float* __restrict__ x,
                const unsigned long long* __restrict__ ws,
                float* __restrict__ out) {
    const int c = threadIdx.x;
    const int b = blockIdx.x;
    const int l = blockIdx.y;
    const int e = l * C_ + c;

    unsigned long long m = 0ull;
#pragma unroll
    for (int chunk = 0; chunk < NCHUNK; ++chunk) {
        const unsigned long long v = ws[((long)chunk * B_ + b) * E_ + e];
        if (v > m) m = v;
    }
    const int n = (int)(~(unsigned int)(m & 0xFFFFFFFFull));

    const int i0 = I0_OF_L[l];
    const int ni = NI_OF_L[l];
    const long src = (((long)b * N_ + n) * IR_ + i0) * C_ + c;
    const long dst = ((long)b * IR_ + i0) * C_ + c;
#pragma unroll 7
    for (int k = 0; k < ni; ++k) {
        out[dst + (long)k * C_] = x[src + (long)k * C_];
    }
}

extern "C" void kernel_launch(void* const* d_in, const int* in_sizes, int n_in,
                              void* d_out, int out_size, void* d_ws, size_t ws_size,
                              hipStream_t stream) {
    const float* x = (const float*)d_in[0];
    // d_in[1] (i2l) is a fixed 0/1 indicator for LMAX=3 — hardcoded as L_OF_I.
    unsigned long long* ws = (unsigned long long*)d_ws;
    float* out = (float*)d_out;

    // ws[NCHUNK][B_][E_] = 4 MiB, fully written by phase1 before phase2 reads it
    // (same stream -> ordered). No memset, no atomics.
    dim3 g1(NCHUNK, B_);
    cmp_phase1<<<g1, 128, 0, stream>>>(x, ws);
    dim3 g2(B_, NL_);
    cmp_phase2<<<g2, 128, 0, stream>>>(x, ws, out);
}